// Round 1
// baseline (11.749 us; speedup 1.0000x reference)
//
#include <hip/hip_runtime.h>

#define POOL 7
#define NCELL (POOL * POOL * POOL)   // 343
#define NUM_ROIS 64
#define DIMD 128
#define DIMH 128
#define DIMW 128
#define CH 32

__device__ __forceinline__ void axis_coords(int start, int size, int dim, int p,
                                            int& i0, int& i1, float& w) {
    float c = (float)start + ((float)p + 0.5f) * ((float)size / (float)POOL) - 0.5f;
    c = fminf(fmaxf(c, 0.0f), (float)(dim - 1));
    float f = floorf(c);
    i0 = (int)f;
    i1 = min(i0 + 1, dim - 1);
    w = c - f;
}

__global__ __launch_bounds__(256) void roi_align_3d(const float* __restrict__ img,
                                                    const int* __restrict__ rois,
                                                    float* __restrict__ out) {
    const int tid = threadIdx.x;
    const int c = tid & 31;           // channel
    const int cell_in_blk = tid >> 5; // 0..7
    const int roi = blockIdx.y;
    const int cell = blockIdx.x * 8 + cell_in_blk;
    if (cell >= NCELL) return;

    const int px = cell / (POOL * POOL);
    const int rem = cell - px * (POOL * POOL);
    const int py = rem / POOL;
    const int pz = rem - py * POOL;

    const int* r = rois + roi * 6;
    const int sx = r[0], sy = r[1], sz = r[2];
    const int ex = r[3], ey = r[4], ez = r[5];

    int x0, x1, y0, y1, z0, z1;
    float wx, wy, wz;
    axis_coords(sx, ex, DIMD, px, x0, x1, wx);
    axis_coords(sy, ey, DIMH, py, y0, y1, wy);
    axis_coords(sz, ez, DIMW, pz, z0, z1, wz);

    const long sD = (long)DIMH * DIMW * CH;  // 524288
    const long sH = (long)DIMW * CH;         // 4096
    const long sW = CH;                      // 32

    const long bx0 = (long)x0 * sD, bx1 = (long)x1 * sD;
    const long by0 = (long)y0 * sH, by1 = (long)y1 * sH;
    const long bz0 = (long)z0 * sW + c, bz1 = (long)z1 * sW + c;

    const float v000 = img[bx0 + by0 + bz0];
    const float v001 = img[bx0 + by0 + bz1];
    const float v010 = img[bx0 + by1 + bz0];
    const float v011 = img[bx0 + by1 + bz1];
    const float v100 = img[bx1 + by0 + bz0];
    const float v101 = img[bx1 + by0 + bz1];
    const float v110 = img[bx1 + by1 + bz0];
    const float v111 = img[bx1 + by1 + bz1];

    const float ux = 1.0f - wx, uy = 1.0f - wy, uz = 1.0f - wz;

    float acc = v000 * (ux * uy * uz)
              + v100 * (wx * uy * uz)
              + v010 * (ux * wy * uz)
              + v110 * (wx * wy * uz)
              + v001 * (ux * uy * wz)
              + v101 * (wx * uy * wz)
              + v011 * (ux * wy * wz)
              + v111 * (wx * wy * wz);

    out[((long)roi * NCELL + cell) * CH + c] = acc;
}

extern "C" void kernel_launch(void* const* d_in, const int* in_sizes, int n_in,
                              void* d_out, int out_size, void* d_ws, size_t ws_size,
                              hipStream_t stream) {
    const float* img = (const float*)d_in[0];
    const int* rois = (const int*)d_in[1];
    float* out = (float*)d_out;

    dim3 grid((NCELL + 7) / 8, NUM_ROIS);
    roi_align_3d<<<grid, 256, 0, stream>>>(img, rois, out);
}